// Round 12
// baseline (603.309 us; speedup 1.0000x reference)
//
#include <hip/hip_runtime.h>
#include <hip/hip_bf16.h>
#include <math.h>

// T=4096, B=4, S=16 -> BS=64, F=64, CH=97 (16 B | 16 C | 1 A | 64 X), K=5.
// Output: (T, B, S) float32, flat index t*64 + bs.
//
// ROUND 15: single-pass SSD via decoupled-lookback chain.
//  - The inter-chunk scan is fused INTO k_fwd: block (ci,bs) publishes its
//    inclusive affine state N = d*N_prev + sred to workspace (device-scope
//    atomics), after polling predecessor (ci-1,bs)'s flag. sns = N_prev.
//  - Deadlock-safe: atomic ticket -> (bs=t&63, ci=t>>6); a block only waits
//    on strictly-earlier tickets (grounded at ci=0). Flags/ticket zeroed by
//    k_prep each launch (stream-ordered, graph-safe).
//  - out written directly from registers (C rows already live) -> k_out
//    deleted; Cm_t (16.8 MB W + 16.8 MB R), Acs, yp, sred, csum round-trips
//    all eliminated. WRITE_SIZE 18.8 -> ~2 MB.
//  - r6 lesson: ci%8 already determined XCD under the 2-D grid (the r14
//    "swizzle" was a no-op); x has no cross-bs reuse, so ticket-based
//    (bs,ci) assignment costs no locality.

#define Tn 4096
#define BSn 64
#define Fn 64
#define CHn 97
#define CHP 112   // padded channels for MFMA (7 tiles of 16); ch97 = pass_w@k4
#define Kn 5
#define Nn 16
#define NCn 64

typedef __attribute__((ext_vector_type(8))) short bf16x8;
typedef __attribute__((ext_vector_type(4))) float f32x4;

static __device__ __forceinline__ unsigned short f2bf(float v) {
    __hip_bfloat16 b = __float2bfloat16(v);
    return *reinterpret_cast<unsigned short*>(&b);
}
static __device__ __forceinline__ float bf2f(unsigned short u) {
    unsigned v = ((unsigned)u) << 16;
    return __builtin_bit_cast(float, v);
}

// ---------------- workspace layout (float units) ----------------
// end = OFF_WBL + 2560 = 9,592,832 fl = 38,371,328 B < validated envelope.
#define OFF_BD   0                      // chain region (inside old BD space)
#define OFF_CHS  OFF_BD                 // Schain: [64*64][16] floats
#define OFF_FLG  (OFF_BD + 65536)       // flags:  4096 ints
#define OFF_TKT  (OFF_BD + 69888)       // ticket: 1 int
#define OFF_CM   (OFF_BD + 4194304)     // (unused)
#define OFF_LAD  (OFF_CM + 4194304)     // (unused)
#define OFF_XQ   (OFF_LAD + 262144)     // (unused)
#define OFF_DL   (OFF_XQ + 262144)      // (unused)
#define OFF_ACS  (OFF_DL + 262144)      // (unused)
#define OFF_SRED (OFF_ACS + 262144)     // (unused)
#define OFF_CSUM (OFF_SRED + 65536)     // (unused)
#define OFF_SNS  (OFF_CSUM + 4096)      // (unused)
#define OFF_WBH  (OFF_SNS + 65536)      // bf16 [k][112][64]
#define OFF_WBL  (OFF_WBH + 17920)      // bf16 lo-residual [k][16][64] (ch32..47)

// K0: weight prep + chain-state reset (flags, ticket) for this launch/replay.
__global__ __launch_bounds__(256) void k_prep(const float* __restrict__ conv_w,
                                              const float* __restrict__ pass_w,
                                              unsigned short* __restrict__ wbh,
                                              unsigned short* __restrict__ wbl,
                                              int* __restrict__ flags,
                                              int* __restrict__ ticket) {
    int idx = blockIdx.x * 256 + threadIdx.x;
    if (idx < NCn * BSn) flags[idx] = 0;
    if (idx == NCn * BSn) *ticket = 0;
    if (idx >= Kn * CHP * Fn) return;
    int f = idx & 63;
    int rest = idx >> 6;
    int ch = rest % CHP;
    int k = rest / CHP;
    float w = 0.f;
    if (ch < CHn) w = conv_w[(ch * Fn + f) * Kn + k];
    else if (ch == 97 && k == 4) w = pass_w[f];
    unsigned short hi = f2bf(w);
    wbh[idx] = hi;
    if (ch >= 32 && ch < 48)
        wbl[(k * 16 + (ch - 32)) * 64 + f] = f2bf(w - bf2f(hi));
}

// K1: fully fused SSD forward. Block = ticket -> (bs, ci), 256 thr = 4 waves.
// Tile-per-wave (validated): wv0: ct0(B)+ct4; wv1: ct1(C)+ct5; wv2: ct2+
// residual (A f32-exact); wv3: ct3+ct6 (ch96, Dx ch97).
__global__ __launch_bounds__(256) void k_fwd(
    const float* __restrict__ x, const unsigned short* __restrict__ wbh,
    const unsigned short* __restrict__ wbl,
    const float* __restrict__ conv_b, const float* __restrict__ pass_b,
    const float* __restrict__ red_w, const float* __restrict__ red_b,
    const float* __restrict__ dtp,
    float* __restrict__ Schain, int* __restrict__ flags,
    int* __restrict__ ticket, float* __restrict__ out) {
    const int tid = threadIdx.x;
    const int wv = tid >> 6, lane = tid & 63;
    const int qd = lane >> 4, n = lane & 15;

    // LDS pool: phase A: xsb[68*72] + xlo[68*72] bf16 (19584 B).
    // phase B (union): B0[64][20] | Ct[64][20] | pxl[4][64] | px2[4][64] |
    //   zsh[64] | dl[64] | sn[16]  (12864 B <= 19584).
    __shared__ alignas(16) unsigned char pool[19584];
    unsigned short* xsb = (unsigned short*)pool;
    unsigned short* xlo = (unsigned short*)(pool + 9792);
    float* B0  = (float*)pool;            // [64][20]
    float* Ct  = (float*)(pool + 5120);   // [64][20]
    float* pxl = (float*)(pool + 10240);  // [4][64]
    float* px2 = (float*)(pool + 11264);  // [4][64]
    float* zsh = (float*)(pool + 12288);  // [64]
    float* dl  = (float*)(pool + 12544);  // [64]
    float* sn  = (float*)(pool + 12800);  // [16]
    __shared__ int tkt_s;

    // ---- ticket: start-order = ticket-order makes the chain deadlock-free
    if (tid == 0) tkt_s = atomicAdd(ticket, 1);
    __syncthreads();
    const int bs = tkt_s & 63, ci = tkt_s >> 6;

    // ---- hoisted weight loads (validated): 20 bf16x8/lane, issued FIRST
    const int tB = (wv == 3) ? 6 : wv + 4;               // wv2: unused
    const unsigned short* pBw = (wv == 2) ? wbl : wbh;
    const int sB = (wv == 2) ? 16 : CHP;
    const int cB = (wv == 2) ? 0 : 16 * tB;
    bf16x8 wA[10], wB[10];
#pragma unroll
    for (int s = 0; s < 10; ++s) {
        const int k = s >> 1, f0 = 32 * (s & 1) + qd * 8;
        wA[s] = *(const bf16x8*)&wbh[((k * CHP + 16 * wv + n) << 6) + f0];
        wB[s] = *(const bf16x8*)&pBw[((k * sB + cB + n) << 6) + f0];
    }

    // ---- batched x staging
    float4 v[5];
#pragma unroll
    for (int it = 0; it < 5; ++it) {
        int idx = tid + it * 256;
        int tt = idx >> 4, fq = (idx & 15) * 4;
        int t = ci * 64 - 4 + tt;
        v[it] = (idx < 68 * 16 && t >= 0)
                    ? *(const float4*)&x[(t * 64 + bs) * 64 + fq]
                    : make_float4(0.f, 0.f, 0.f, 0.f);
    }
#pragma unroll
    for (int it = 0; it < 5; ++it) {
        int idx = tid + it * 256;
        if (idx < 68 * 16) {
            int tt = idx >> 4, fq = (idx & 15) * 4;
            ushort4 h, lo;
            h.x = f2bf(v[it].x); lo.x = f2bf(v[it].x - bf2f(h.x));
            h.y = f2bf(v[it].y); lo.y = f2bf(v[it].y - bf2f(h.y));
            h.z = f2bf(v[it].z); lo.z = f2bf(v[it].z - bf2f(h.z));
            h.w = f2bf(v[it].w); lo.w = f2bf(v[it].w - bf2f(h.w));
            *(ushort4*)&xsb[tt * 72 + fq] = h;
            *(ushort4*)&xlo[tt * 72 + fq] = lo;
        }
    }
    __syncthreads();  // b1: stage done (drains hoisted weight loads too)

    // ---- MFMA (validated)
    f32x4 accA[4], accB[4];
#pragma unroll
    for (int rg = 0; rg < 4; ++rg) {
        accA[rg] = (f32x4){0.f, 0.f, 0.f, 0.f};
        accB[rg] = (f32x4){0.f, 0.f, 0.f, 0.f};
    }
    if (wv == 2) {
#pragma unroll
        for (int s = 0; s < 10; ++s) {
            const int k = s >> 1, f0 = 32 * (s & 1) + qd * 8;
#pragma unroll
            for (int rg = 0; rg < 4; ++rg) {
                bf16x8 av = *(const bf16x8*)&xsb[(16 * rg + n + k) * 72 + f0];
                bf16x8 al = *(const bf16x8*)&xlo[(16 * rg + n + k) * 72 + f0];
                accA[rg] = __builtin_amdgcn_mfma_f32_16x16x32_bf16(av, wA[s], accA[rg], 0, 0, 0);
                accA[rg] = __builtin_amdgcn_mfma_f32_16x16x32_bf16(al, wA[s], accA[rg], 0, 0, 0);
                accA[rg] = __builtin_amdgcn_mfma_f32_16x16x32_bf16(av, wB[s], accA[rg], 0, 0, 0);
            }
        }
    } else {
#pragma unroll
        for (int s = 0; s < 10; ++s) {
            const int k = s >> 1, f0 = 32 * (s & 1) + qd * 8;
#pragma unroll
            for (int rg = 0; rg < 4; ++rg) {
                bf16x8 av = *(const bf16x8*)&xsb[(16 * rg + n + k) * 72 + f0];
                accA[rg] = __builtin_amdgcn_mfma_f32_16x16x32_bf16(av, wA[s], accA[rg], 0, 0, 0);
                accB[rg] = __builtin_amdgcn_mfma_f32_16x16x32_bf16(av, wB[s], accB[rg], 0, 0, 0);
            }
        }
    }
    __syncthreads();  // b2: MFMA done; xsb/xlo lifetime ends (union -> phase B)

    // ---- activation phase (validated; Cm_t global write removed)
    float px[4][4];
#pragma unroll
    for (int rg = 0; rg < 4; ++rg)
#pragma unroll
        for (int reg = 0; reg < 4; ++reg) px[rg][reg] = 0.f;

    if (wv == 0) {
        const float cb0 = conv_b[n];
        const float cb4 = conv_b[64 + n], rw4 = red_w[31 + n];
#pragma unroll
        for (int rg = 0; rg < 4; ++rg)
#pragma unroll
            for (int reg = 0; reg < 4; ++reg) {
                int row = 16 * rg + 4 * qd + reg;
                float z0 = accA[rg][reg] + cb0;
                float a0 = z0 + 1.f / (1.f + __expf(-z0));
                accA[rg][reg] = a0;          // keep for sred
                B0[row * 20 + n] = a0;
                float z4 = accB[rg][reg] + cb4;
                px[rg][reg] = (z4 + 1.f / (1.f + __expf(-z4))) * rw4;
            }
    } else if (wv == 1) {
        const float cb1 = conv_b[16 + n];
        const float cb5 = conv_b[80 + n], rw5 = red_w[47 + n];
#pragma unroll
        for (int rg = 0; rg < 4; ++rg)
#pragma unroll
            for (int reg = 0; reg < 4; ++reg) {
                int row = 16 * rg + 4 * qd + reg;
                float z1 = accA[rg][reg] + cb1;
                Ct[row * 20 + n] = z1 + 1.f / (1.f + __expf(-z1));
                float z5 = accB[rg][reg] + cb5;
                px[rg][reg] = (z5 + 1.f / (1.f + __expf(-z5))) * rw5;
            }
    } else if (wv == 2) {
        const float cb2 = conv_b[32 + n];
        const float rw2 = (n >= 1) ? red_w[n - 1] : 0.f;
#pragma unroll
        for (int rg = 0; rg < 4; ++rg)
#pragma unroll
            for (int reg = 0; reg < 4; ++reg) {
                int row = 16 * rg + 4 * qd + reg;
                if (n == 0) zsh[row] = accA[rg][reg];   // raw A acc
                float z = accA[rg][reg] + cb2;
                px[rg][reg] = (z + 1.f / (1.f + __expf(-z))) * rw2;
            }
    } else {
        const float cb3 = conv_b[48 + n], rw3 = red_w[15 + n];
        const float cb6 = conv_b[96], rw6 = red_w[63];
        const float pb = pass_b[0], rb = red_b[0];
#pragma unroll
        for (int rg = 0; rg < 4; ++rg)
#pragma unroll
            for (int reg = 0; reg < 4; ++reg) {
                int row = 16 * rg + 4 * qd + reg;
                float z3 = accA[rg][reg] + cb3;
                px[rg][reg] = (z3 + 1.f / (1.f + __expf(-z3))) * rw3;
                if (n == 0) {  // ch96 X channel
                    float z6 = accB[rg][reg] + cb6;
                    px[rg][reg] += (z6 + 1.f / (1.f + __expf(-z6))) * rw6;
                }
                if (n == 1) {  // ch97 = Dx (raw)
                    float Dx = accB[rg][reg] + pb;
                    float DL = (Dx >= 0.f) ? Dx : 0.01f * Dx;
                    dl[row] = DL + rb;
                }
            }
    }
    // xq partials: reduce px over the 16 'n' lanes
#pragma unroll
    for (int m = 1; m < 16; m <<= 1)
#pragma unroll
        for (int rg = 0; rg < 4; ++rg)
#pragma unroll
            for (int reg = 0; reg < 4; ++reg)
                px[rg][reg] += __shfl_xor(px[rg][reg], m, 64);
    if (n == 0)
#pragma unroll
        for (int rg = 0; rg < 4; ++rg)
#pragma unroll
            for (int reg = 0; reg < 4; ++reg)
                pxl[wv * 64 + 16 * rg + 4 * qd + reg] = px[rg][reg];
    __syncthreads();  // b3: B0, Ct, pxl, zsh, dl ready

    // ---- scan phase (replicated per wave, lane = chunk row l)
    const int l = lane;
    const float dt = log1pf(expf(dtp[0])) + 0.01f;
    float zA = zsh[l] + conv_b[32];
    float aA = zA + 1.f / (1.f + __expf(-zA));
    float An = -fabsf(aA);
    float lAd = dt * An;
    float fac = (__expf(lAd) - 1.f) / (An + 1e-9f);
    float s = lAd;  // inclusive Kogge-Stone scan over 64 lanes
#pragma unroll
    for (int k = 1; k < 64; k <<= 1) {
        float t2 = __shfl_up(s, k, 64);
        if (l >= k) s += t2;
    }
    const float acs_l = s;
    const float tot = __shfl(s, 63, 64);
    float xq = pxl[0 * 64 + l] + pxl[1 * 64 + l] + pxl[2 * 64 + l] + pxl[3 * 64 + l];
    const float wd = fac * xq;                                // diag weight
    const float wsd = wd * __expf(fmaxf(tot - acs_l, -20.f)); // state weight

    // ---- wv0: sred from live a0 regs, then the lookback chain (publish ASAP)
    if (wv == 0) {
        float sp = 0.f;
#pragma unroll
        for (int rg = 0; rg < 4; ++rg)
#pragma unroll
            for (int reg = 0; reg < 4; ++reg)
                sp += accA[rg][reg] * __shfl(wsd, 16 * rg + 4 * qd + reg, 64);
        sp += __shfl_xor(sp, 16, 64);
        sp += __shfl_xor(sp, 32, 64);
        // lanes n<16 (qd==0) hold sred[n]
        if (lane < 16) {
            const float dloc = __expf(tot);  // csum <= 0 -> dloc <= 1
            float nprev = 0.f;
            if (ci > 0) {
                int* fp = &flags[bs * 64 + (ci - 1)];
                long spin = 0;
                while (__hip_atomic_load(fp, __ATOMIC_ACQUIRE,
                                         __HIP_MEMORY_SCOPE_AGENT) == 0) {
                    __builtin_amdgcn_s_sleep(2);
                    if (++spin > 100000000L) break;  // bail: absmax will flag
                }
                nprev = __hip_atomic_load(
                    &Schain[(bs * 64 + (ci - 1)) * 16 + lane],
                    __ATOMIC_RELAXED, __HIP_MEMORY_SCOPE_AGENT);
            }
            sn[lane] = nprev;  // sns for this chunk
            if (ci < NCn - 1) {
                __hip_atomic_store(&Schain[(bs * 64 + ci) * 16 + lane],
                                   dloc * nprev + sp, __ATOMIC_RELAXED,
                                   __HIP_MEMORY_SCOPE_AGENT);
                __builtin_amdgcn_s_waitcnt(0);  // drain before flag
                if (lane == 0)
                    __hip_atomic_store(&flags[bs * 64 + ci], 1,
                                       __ATOMIC_RELEASE,
                                       __HIP_MEMORY_SCOPE_AGENT);
            }
        }
    }

    // ---- Y_diag: wave wv covers m in [16wv, 16wv+16)
    const float4 cc0 = *(const float4*)&Ct[l * 20 + 0];
    const float4 cc1 = *(const float4*)&Ct[l * 20 + 4];
    const float4 cc2 = *(const float4*)&Ct[l * 20 + 8];
    const float4 cc3 = *(const float4*)&Ct[l * 20 + 12];
    float part = 0.f;
#pragma unroll
    for (int mm = 0; mm < 16; ++mm) {
        const int m = 16 * wv + mm;
        const float4 b0 = *(const float4*)&B0[m * 20 + 0];   // broadcast
        const float4 b1 = *(const float4*)&B0[m * 20 + 4];
        const float4 b2 = *(const float4*)&B0[m * 20 + 8];
        const float4 b3 = *(const float4*)&B0[m * 20 + 12];
        float g = cc0.x * b0.x + cc0.y * b0.y + cc0.z * b0.z + cc0.w * b0.w +
                  cc1.x * b1.x + cc1.y * b1.y + cc1.z * b1.z + cc1.w * b1.w +
                  cc2.x * b2.x + cc2.y * b2.y + cc2.z * b2.z + cc2.w * b2.w +
                  cc3.x * b3.x + cc3.y * b3.y + cc3.z * b3.z + cc3.w * b3.w;
        float am = __shfl(acs_l, m, 64);
        float wm = __shfl(wd, m, 64);
        float arg = (m <= l) ? fmaxf(acs_l - am, -20.f) : -20.f;
        part += __expf(arg) * g * wm;
    }
    px2[wv * 64 + l] = part;
    __syncthreads();  // b4: px2 + sn ready

    if (wv == 0) {
        float go = cc0.x * sn[0] + cc0.y * sn[1] + cc0.z * sn[2] + cc0.w * sn[3] +
                   cc1.x * sn[4] + cc1.y * sn[5] + cc1.z * sn[6] + cc1.w * sn[7] +
                   cc2.x * sn[8] + cc2.y * sn[9] + cc2.z * sn[10] + cc2.w * sn[11] +
                   cc3.x * sn[12] + cc3.y * sn[13] + cc3.z * sn[14] + cc3.w * sn[15];
        float yv = px2[0 * 64 + l] + px2[1 * 64 + l] + px2[2 * 64 + l] +
                   px2[3 * 64 + l] + dl[l] + __expf(acs_l) * go;
        out[(ci * 64 + l) * 64 + bs] = yv;
    }
}

extern "C" void kernel_launch(void* const* d_in, const int* in_sizes, int n_in,
                              void* d_out, int out_size, void* d_ws,
                              size_t ws_size, hipStream_t stream) {
    const float* x = (const float*)d_in[0];
    const float* conv_w = (const float*)d_in[1];
    const float* conv_b = (const float*)d_in[2];
    const float* pass_w = (const float*)d_in[3];
    const float* pass_b = (const float*)d_in[4];
    const float* red_w = (const float*)d_in[5];
    const float* red_b = (const float*)d_in[6];
    const float* dtp = (const float*)d_in[7];
    float* out = (float*)d_out;
    float* W = (float*)d_ws;
    (void)in_sizes; (void)n_in; (void)out_size; (void)ws_size;

    float* Schain = W + OFF_CHS;
    int* flags = (int*)(W + OFF_FLG);
    int* ticket = (int*)(W + OFF_TKT);
    unsigned short* wbh = (unsigned short*)(W + OFF_WBH);
    unsigned short* wbl = (unsigned short*)(W + OFF_WBL);

    k_prep<<<dim3((Kn * CHP * Fn + 255) / 256), dim3(256), 0, stream>>>(
        conv_w, pass_w, wbh, wbl, flags, ticket);
    k_fwd<<<dim3(NCn * BSn), dim3(256), 0, stream>>>(
        x, wbh, wbl, conv_b, pass_b, red_w, red_b, dtp,
        Schain, flags, ticket, out);
}

// Round 16
// 199.591 us; speedup vs baseline: 3.0227x; 3.0227x over previous
//
#include <hip/hip_runtime.h>
#include <hip/hip_bf16.h>
#include <math.h>

// T=4096, B=4, S=16 -> BS=64, F=64, CH=97 (16 B | 16 C | 1 A | 64 X), K=5.
// Output: (T, B, S) float32, flat index t*64 + bs.
//
// ROUND 17: r6/r8-validated 3-kernel structure (202.0 us, absmax 0.5) +
// Cm stored as bf16 (was f32). Cm is only consumed by k_out's C·sns dot;
// Y_diag keeps the f32 LDS copy, so only the Y_off term sees bf16 rounding
// (~0.2% rel). Traffic: Cm round-trip 33.6 MB -> 16.8 MB, the largest
// single item in the ~85 us tail.
// (r12 lesson: cross-block serial chains ~7us/link = dead. r15 lesson:
// cooperative launch failed correctness/launch — structural tail-deletion
// is high-risk; bank traffic wins on the validated structure instead.)

#define Tn 4096
#define BSn 64
#define Fn 64
#define CHn 97
#define CHP 112   // padded channels for MFMA (7 tiles of 16); ch97 = pass_w@k4
#define Kn 5
#define NCn 64

typedef __attribute__((ext_vector_type(8))) short bf16x8;
typedef __attribute__((ext_vector_type(4))) float f32x4;

static __device__ __forceinline__ unsigned short f2bf(float v) {
    __hip_bfloat16 b = __float2bfloat16(v);
    return *reinterpret_cast<unsigned short*>(&b);
}
static __device__ __forceinline__ float bf2f(unsigned short u) {
    unsigned v = ((unsigned)u) << 16;
    return __builtin_bit_cast(float, v);
}
static __device__ __forceinline__ float bflo(unsigned u) {  // low bf16 of u32
    return __builtin_bit_cast(float, u << 16);
}
static __device__ __forceinline__ float bfhi(unsigned u) {  // high bf16 of u32
    return __builtin_bit_cast(float, u & 0xffff0000u);
}

// ---------------- workspace layout (float units) ----------------
// end = OFF_WBL + 2560 = 9,592,832 fl = 38,371,328 B < validated envelope.
#define OFF_BD   0                      // (unused)
#define OFF_CM   (OFF_BD + 4194304)     // Cm as bf16: uses half the region
#define OFF_LAD  (OFF_CM + 4194304)     // (unused)
#define OFF_XQ   (OFF_LAD + 262144)     // (unused)
#define OFF_DL   (OFF_XQ + 262144)      // yp_ws
#define OFF_ACS  (OFF_DL + 262144)
#define OFF_SRED (OFF_ACS + 262144)
#define OFF_CSUM (OFF_SRED + 65536)
#define OFF_SNS  (OFF_CSUM + 4096)      // (unused)
#define OFF_WBH  (OFF_SNS + 65536)      // bf16 [k][112][64]
#define OFF_WBL  (OFF_WBH + 17920)      // bf16 lo-residual [k][16][64] (ch32..47)

// K0: weight prep. ch<97: conv_w; ch97,k=4: pass_w (Dx-as-GEMM row); else 0.
__global__ __launch_bounds__(256) void k_prep(const float* __restrict__ conv_w,
                                              const float* __restrict__ pass_w,
                                              unsigned short* __restrict__ wbh,
                                              unsigned short* __restrict__ wbl) {
    int idx = blockIdx.x * 256 + threadIdx.x;
    if (idx >= Kn * CHP * Fn) return;
    int f = idx & 63;
    int rest = idx >> 6;
    int ch = rest % CHP;
    int k = rest / CHP;
    float w = 0.f;
    if (ch < CHn) w = conv_w[(ch * Fn + f) * Kn + k];
    else if (ch == 97 && k == 4) w = pass_w[f];
    unsigned short hi = f2bf(w);
    wbh[idx] = hi;
    if (ch >= 32 && ch < 48)
        wbl[(k * 16 + (ch - 32)) * 64 + f] = f2bf(w - bf2f(hi));
}

// K1: fused conv + chunk + Y_diag (r6/r8-validated; Cm write now bf16).
// Tile-per-wave: wv0: ct0(B)+ct4; wv1: ct1(C)+ct5; wv2: ct2+residual
// (A f32-exact); wv3: ct3+ct6 (ch96, Dx ch97).
__global__ __launch_bounds__(256) void k_fwd(
    const float* __restrict__ x, const unsigned short* __restrict__ wbh,
    const unsigned short* __restrict__ wbl,
    const float* __restrict__ conv_b, const float* __restrict__ pass_b,
    const float* __restrict__ red_w, const float* __restrict__ red_b,
    const float* __restrict__ dtp,
    unsigned short* __restrict__ Cm_h, float* __restrict__ Acs_ws,
    float* __restrict__ yp_ws, float* __restrict__ sred_ws,
    float* __restrict__ csum_ws) {
    const int wgid = blockIdx.x;
    const int seq = wgid >> 3;
    const int bs = seq & 63;
    const int ci = ((seq >> 6) << 3) | (wgid & 7);
    const int tid = threadIdx.x;
    const int wv = tid >> 6, lane = tid & 63;
    const int qd = lane >> 4, n = lane & 15;

    // LDS pool: phase A: xsb[68*72] + xlo[68*72] bf16 (19584 B).
    // phase B (union): B0[64][20] | Ct[64][20] | pxl[4][64] | px2[4][64] |
    //   zsh[64] | dl[64]  (12800 B <= 19584).
    __shared__ alignas(16) unsigned char pool[19584];
    unsigned short* xsb = (unsigned short*)pool;
    unsigned short* xlo = (unsigned short*)(pool + 9792);
    float* B0  = (float*)pool;            // [64][20]
    float* Ct  = (float*)(pool + 5120);   // [64][20]
    float* pxl = (float*)(pool + 10240);  // [4][64]
    float* px2 = (float*)(pool + 11264);  // [4][64]
    float* zsh = (float*)(pool + 12288);  // [64]
    float* dl  = (float*)(pool + 12544);  // [64]

    // ---- hoisted weight loads (validated): 20 bf16x8/lane, issued FIRST
    const int tB = (wv == 3) ? 6 : wv + 4;               // wv2: unused
    const unsigned short* pBw = (wv == 2) ? wbl : wbh;
    const int sB = (wv == 2) ? 16 : CHP;
    const int cB = (wv == 2) ? 0 : 16 * tB;
    bf16x8 wA[10], wB[10];
#pragma unroll
    for (int s = 0; s < 10; ++s) {
        const int k = s >> 1, f0 = 32 * (s & 1) + qd * 8;
        wA[s] = *(const bf16x8*)&wbh[((k * CHP + 16 * wv + n) << 6) + f0];
        wB[s] = *(const bf16x8*)&pBw[((k * sB + cB + n) << 6) + f0];
    }

    // ---- batched x staging
    float4 v[5];
#pragma unroll
    for (int it = 0; it < 5; ++it) {
        int idx = tid + it * 256;
        int tt = idx >> 4, fq = (idx & 15) * 4;
        int t = ci * 64 - 4 + tt;
        v[it] = (idx < 68 * 16 && t >= 0)
                    ? *(const float4*)&x[(t * 64 + bs) * 64 + fq]
                    : make_float4(0.f, 0.f, 0.f, 0.f);
    }
#pragma unroll
    for (int it = 0; it < 5; ++it) {
        int idx = tid + it * 256;
        if (idx < 68 * 16) {
            int tt = idx >> 4, fq = (idx & 15) * 4;
            ushort4 h, lo;
            h.x = f2bf(v[it].x); lo.x = f2bf(v[it].x - bf2f(h.x));
            h.y = f2bf(v[it].y); lo.y = f2bf(v[it].y - bf2f(h.y));
            h.z = f2bf(v[it].z); lo.z = f2bf(v[it].z - bf2f(h.z));
            h.w = f2bf(v[it].w); lo.w = f2bf(v[it].w - bf2f(h.w));
            *(ushort4*)&xsb[tt * 72 + fq] = h;
            *(ushort4*)&xlo[tt * 72 + fq] = lo;
        }
    }
    __syncthreads();  // b1: stage done (drains hoisted weight loads too)

    // ---- MFMA (validated)
    f32x4 accA[4], accB[4];
#pragma unroll
    for (int rg = 0; rg < 4; ++rg) {
        accA[rg] = (f32x4){0.f, 0.f, 0.f, 0.f};
        accB[rg] = (f32x4){0.f, 0.f, 0.f, 0.f};
    }
    if (wv == 2) {
#pragma unroll
        for (int s = 0; s < 10; ++s) {
            const int k = s >> 1, f0 = 32 * (s & 1) + qd * 8;
#pragma unroll
            for (int rg = 0; rg < 4; ++rg) {
                bf16x8 av = *(const bf16x8*)&xsb[(16 * rg + n + k) * 72 + f0];
                bf16x8 al = *(const bf16x8*)&xlo[(16 * rg + n + k) * 72 + f0];
                accA[rg] = __builtin_amdgcn_mfma_f32_16x16x32_bf16(av, wA[s], accA[rg], 0, 0, 0);
                accA[rg] = __builtin_amdgcn_mfma_f32_16x16x32_bf16(al, wA[s], accA[rg], 0, 0, 0);
                accA[rg] = __builtin_amdgcn_mfma_f32_16x16x32_bf16(av, wB[s], accA[rg], 0, 0, 0);
            }
        }
    } else {
#pragma unroll
        for (int s = 0; s < 10; ++s) {
            const int k = s >> 1, f0 = 32 * (s & 1) + qd * 8;
#pragma unroll
            for (int rg = 0; rg < 4; ++rg) {
                bf16x8 av = *(const bf16x8*)&xsb[(16 * rg + n + k) * 72 + f0];
                accA[rg] = __builtin_amdgcn_mfma_f32_16x16x32_bf16(av, wA[s], accA[rg], 0, 0, 0);
                accB[rg] = __builtin_amdgcn_mfma_f32_16x16x32_bf16(av, wB[s], accB[rg], 0, 0, 0);
            }
        }
    }
    __syncthreads();  // b2: MFMA done; xsb/xlo lifetime ends (union -> phase B)

    // ---- activation phase (validated; Cm stored bf16)
    const int cbase = (bs * 64 + ci) * 64;
    float px[4][4];
#pragma unroll
    for (int rg = 0; rg < 4; ++rg)
#pragma unroll
        for (int reg = 0; reg < 4; ++reg) px[rg][reg] = 0.f;

    if (wv == 0) {
        const float cb0 = conv_b[n];
        const float cb4 = conv_b[64 + n], rw4 = red_w[31 + n];
#pragma unroll
        for (int rg = 0; rg < 4; ++rg)
#pragma unroll
            for (int reg = 0; reg < 4; ++reg) {
                int row = 16 * rg + 4 * qd + reg;
                float z0 = accA[rg][reg] + cb0;
                float a0 = z0 + 1.f / (1.f + __expf(-z0));
                accA[rg][reg] = a0;          // keep for sred
                B0[row * 20 + n] = a0;
                float z4 = accB[rg][reg] + cb4;
                px[rg][reg] = (z4 + 1.f / (1.f + __expf(-z4))) * rw4;
            }
    } else if (wv == 1) {
        const float cb1 = conv_b[16 + n];
        const float cb5 = conv_b[80 + n], rw5 = red_w[47 + n];
#pragma unroll
        for (int rg = 0; rg < 4; ++rg)
#pragma unroll
            for (int reg = 0; reg < 4; ++reg) {
                int row = 16 * rg + 4 * qd + reg;
                float z1 = accA[rg][reg] + cb1;
                float a1 = z1 + 1.f / (1.f + __expf(-z1));
                Ct[row * 20 + n] = a1;                       // f32 for Y_diag
                Cm_h[(cbase + row) * 16 + n] = f2bf(a1);     // bf16 for Y_off
                float z5 = accB[rg][reg] + cb5;
                px[rg][reg] = (z5 + 1.f / (1.f + __expf(-z5))) * rw5;
            }
    } else if (wv == 2) {
        const float cb2 = conv_b[32 + n];
        const float rw2 = (n >= 1) ? red_w[n - 1] : 0.f;
#pragma unroll
        for (int rg = 0; rg < 4; ++rg)
#pragma unroll
            for (int reg = 0; reg < 4; ++reg) {
                int row = 16 * rg + 4 * qd + reg;
                if (n == 0) zsh[row] = accA[rg][reg];   // raw A acc
                float z = accA[rg][reg] + cb2;
                px[rg][reg] = (z + 1.f / (1.f + __expf(-z))) * rw2;
            }
    } else {
        const float cb3 = conv_b[48 + n], rw3 = red_w[15 + n];
        const float cb6 = conv_b[96], rw6 = red_w[63];
        const float pb = pass_b[0], rb = red_b[0];
#pragma unroll
        for (int rg = 0; rg < 4; ++rg)
#pragma unroll
            for (int reg = 0; reg < 4; ++reg) {
                int row = 16 * rg + 4 * qd + reg;
                float z3 = accA[rg][reg] + cb3;
                px[rg][reg] = (z3 + 1.f / (1.f + __expf(-z3))) * rw3;
                if (n == 0) {  // ch96 X channel
                    float z6 = accB[rg][reg] + cb6;
                    px[rg][reg] += (z6 + 1.f / (1.f + __expf(-z6))) * rw6;
                }
                if (n == 1) {  // ch97 = Dx (raw)
                    float Dx = accB[rg][reg] + pb;
                    float DL = (Dx >= 0.f) ? Dx : 0.01f * Dx;
                    dl[row] = DL + rb;
                }
            }
    }
    // xq partials: reduce px over the 16 'n' lanes
#pragma unroll
    for (int m = 1; m < 16; m <<= 1)
#pragma unroll
        for (int rg = 0; rg < 4; ++rg)
#pragma unroll
            for (int reg = 0; reg < 4; ++reg)
                px[rg][reg] += __shfl_xor(px[rg][reg], m, 64);
    if (n == 0)
#pragma unroll
        for (int rg = 0; rg < 4; ++rg)
#pragma unroll
            for (int reg = 0; reg < 4; ++reg)
                pxl[wv * 64 + 16 * rg + 4 * qd + reg] = px[rg][reg];
    __syncthreads();  // b3: B0, Ct, pxl, zsh, dl ready

    // ---- scan phase (replicated per wave, lane = chunk row l)
    const int l = lane;
    const float dt = log1pf(expf(dtp[0])) + 0.01f;
    float zA = zsh[l] + conv_b[32];
    float aA = zA + 1.f / (1.f + __expf(-zA));
    float An = -fabsf(aA);
    float lAd = dt * An;
    float fac = (__expf(lAd) - 1.f) / (An + 1e-9f);
    float s = lAd;  // inclusive Kogge-Stone scan over 64 lanes
#pragma unroll
    for (int k = 1; k < 64; k <<= 1) {
        float t = __shfl_up(s, k, 64);
        if (l >= k) s += t;
    }
    const float acs_l = s;
    const float tot = __shfl(s, 63, 64);
    float xq = pxl[0 * 64 + l] + pxl[1 * 64 + l] + pxl[2 * 64 + l] + pxl[3 * 64 + l];
    const float wd = fac * xq;                                // diag weight
    const float wsd = wd * __expf(fmaxf(tot - acs_l, -20.f)); // state weight
    if (wv == 3) {
        Acs_ws[bs * Tn + ci * 64 + l] = acs_l;
        if (l == 0) csum_ws[bs * 64 + ci] = tot;
    }

    // ---- Y_diag: wave wv covers m in [16wv, 16wv+16)
    const float4 cc0 = *(const float4*)&Ct[l * 20 + 0];
    const float4 cc1 = *(const float4*)&Ct[l * 20 + 4];
    const float4 cc2 = *(const float4*)&Ct[l * 20 + 8];
    const float4 cc3 = *(const float4*)&Ct[l * 20 + 12];
    float part = 0.f;
#pragma unroll
    for (int mm = 0; mm < 16; ++mm) {
        const int m = 16 * wv + mm;
        const float4 b0 = *(const float4*)&B0[m * 20 + 0];   // broadcast
        const float4 b1 = *(const float4*)&B0[m * 20 + 4];
        const float4 b2 = *(const float4*)&B0[m * 20 + 8];
        const float4 b3 = *(const float4*)&B0[m * 20 + 12];
        float g = cc0.x * b0.x + cc0.y * b0.y + cc0.z * b0.z + cc0.w * b0.w +
                  cc1.x * b1.x + cc1.y * b1.y + cc1.z * b1.z + cc1.w * b1.w +
                  cc2.x * b2.x + cc2.y * b2.y + cc2.z * b2.z + cc2.w * b2.w +
                  cc3.x * b3.x + cc3.y * b3.y + cc3.z * b3.z + cc3.w * b3.w;
        float am = __shfl(acs_l, m, 64);
        float wm = __shfl(wd, m, 64);
        float arg = (m <= l) ? fmaxf(acs_l - am, -20.f) : -20.f;
        part += __expf(arg) * g * wm;
    }
    px2[wv * 64 + l] = part;

    // ---- sred from wv0's live a0 regs: sred[n] = sum_m a0[m,n]*wsd[m]
    if (wv == 0) {
        float sp = 0.f;
#pragma unroll
        for (int rg = 0; rg < 4; ++rg)
#pragma unroll
            for (int reg = 0; reg < 4; ++reg)
                sp += accA[rg][reg] * __shfl(wsd, 16 * rg + 4 * qd + reg, 64);
        sp += __shfl_xor(sp, 16, 64);
        sp += __shfl_xor(sp, 32, 64);
        if (l < 16) sred_ws[(bs * 64 + ci) * 16 + l] = sp;
    }
    __syncthreads();  // b4: px2 ready

    if (wv == 0)
        yp_ws[bs * Tn + ci * 64 + l] =
            px2[0 * 64 + l] + px2[1 * 64 + l] + px2[2 * 64 + l] + px2[3 * 64 + l] + dl[l];
}

// K2: fused inter-chunk scan + output (r6/r8-validated; Cm read now bf16).
// Block = (4 chunks, bs); in-block replicated affine scan then
// out = yp + exp(Acs)*(C·sns).
__global__ __launch_bounds__(256) void k_out(
    const unsigned short* __restrict__ Cm_h, const float* __restrict__ Acs_ws,
    const float* __restrict__ sred_ws, const float* __restrict__ csum_ws,
    const float* __restrict__ yp_ws, float* __restrict__ out) {
    const int bs = blockIdx.y;
    const int tid = threadIdx.x;
    const int wv = tid >> 6, l = tid & 63;
    const int ci = blockIdx.x * 4 + wv;
    __shared__ float sn[4][16];
    const int base = bs * Tn + ci * 64;

    // in-block affine scan (identical math to validated k_scan): lane = chunk
    // id, wave wv handles n = 4*wv .. 4*wv+3.
    const float dexp = __expf(csum_ws[bs * 64 + l]);  // <= 1
#pragma unroll
    for (int j = 0; j < 4; ++j) {
        const int n = 4 * wv + j;
        float s = sred_ws[(bs * 64 + l) * 16 + n];
        float d = dexp;
#pragma unroll
        for (int k = 1; k < 64; k <<= 1) {
            float dp = __shfl_up(d, k, 64);
            float sp = __shfl_up(s, k, 64);
            if (l >= k) {
                s = d * sp + s;  // compose on top of lower segment (old d!)
                d = d * dp;
            }
        }
        float se = __shfl_up(s, 1, 64);
        float sns = (l == 0) ? 0.f : se;
        if ((l >> 2) == blockIdx.x) sn[l & 3][n] = sns;
    }

    const unsigned short* crow = &Cm_h[((bs * 64 + ci) * 64 + l) * 16];
    uint4 ua = *(const uint4*)crow;        // bf16 c0..c7
    uint4 ub = *(const uint4*)(crow + 8);  // bf16 c8..c15
    float yp = yp_ws[base + l];
    float acl = Acs_ws[base + l];
    __syncthreads();

    const float* s = sn[wv];
    float go = bflo(ua.x) * s[0]  + bfhi(ua.x) * s[1] +
               bflo(ua.y) * s[2]  + bfhi(ua.y) * s[3] +
               bflo(ua.z) * s[4]  + bfhi(ua.z) * s[5] +
               bflo(ua.w) * s[6]  + bfhi(ua.w) * s[7] +
               bflo(ub.x) * s[8]  + bfhi(ub.x) * s[9] +
               bflo(ub.y) * s[10] + bfhi(ub.y) * s[11] +
               bflo(ub.z) * s[12] + bfhi(ub.z) * s[13] +
               bflo(ub.w) * s[14] + bfhi(ub.w) * s[15];
    out[(ci * 64 + l) * 64 + bs] = yp + __expf(acl) * go;
}

extern "C" void kernel_launch(void* const* d_in, const int* in_sizes, int n_in,
                              void* d_out, int out_size, void* d_ws,
                              size_t ws_size, hipStream_t stream) {
    const float* x = (const float*)d_in[0];
    const float* conv_w = (const float*)d_in[1];
    const float* conv_b = (const float*)d_in[2];
    const float* pass_w = (const float*)d_in[3];
    const float* pass_b = (const float*)d_in[4];
    const float* red_w = (const float*)d_in[5];
    const float* red_b = (const float*)d_in[6];
    const float* dtp = (const float*)d_in[7];
    float* out = (float*)d_out;
    float* W = (float*)d_ws;
    (void)in_sizes; (void)n_in; (void)out_size; (void)ws_size;

    unsigned short* Cm_h = (unsigned short*)(W + OFF_CM);
    float* yp_ws = W + OFF_DL;
    float* Acs_ws = W + OFF_ACS;
    float* sred_ws = W + OFF_SRED;
    float* csum_ws = W + OFF_CSUM;
    unsigned short* wbh = (unsigned short*)(W + OFF_WBH);
    unsigned short* wbl = (unsigned short*)(W + OFF_WBL);

    k_prep<<<dim3((Kn * CHP * Fn + 255) / 256), dim3(256), 0, stream>>>(
        conv_w, pass_w, wbh, wbl);
    k_fwd<<<dim3(NCn * BSn), dim3(256), 0, stream>>>(
        x, wbh, wbl, conv_b, pass_b, red_w, red_b, dtp,
        Cm_h, Acs_ws, yp_ws, sred_ws, csum_ws);
    k_out<<<dim3(NCn / 4, BSn), dim3(256), 0, stream>>>(
        Cm_h, Acs_ws, sred_ws, csum_ws, yp_ws, out);
}